// Round 8
// baseline (1250.739 us; speedup 1.0000x reference)
//
#include <hip/hip_runtime.h>
#include <math.h>

#define T_TOK 2048
#define HD 768
#define ID 1536
#define NE 8
#define CAP 768
#define TK 4096
#define RT 12      // max 128-row tiles per expert (2*CAP/128)
#define NB1 24     // ID/64 col-strips for gemm1
#define KC1 24     // HD/32 K-steps for gemm1
#define NB2 12     // HD/64 col-strips for gemm2
#define KC2 48     // ID/32 K-steps for gemm2
#define GRID 1024  // 4 blocks/CU x 256 CUs: guaranteed co-resident

typedef __bf16 bf16_t;
typedef __bf16 bf16x8 __attribute__((ext_vector_type(8)));
typedef __bf16 bf16x4 __attribute__((ext_vector_type(4)));
typedef float floatx4 __attribute__((ext_vector_type(4)));

__device__ __forceinline__ void gld16(const bf16_t* g, bf16_t* l) {
  __builtin_amdgcn_global_load_lds(
      (__attribute__((address_space(1))) void*)(g),
      (__attribute__((address_space(3))) void*)(l),
      16, 0, 0);
}

// Monotonic grid barrier: each block adds 1, spins until count >= target.
// Counter zeroed by k_zero before k_moe. Device-scope fences around.
__device__ __forceinline__ void gridbar(int* bar, int target) {
  __threadfence();
  __syncthreads();
  if (threadIdx.x == 0) {
    atomicAdd(bar, 1);
    while (atomicAdd(bar, 0) < target) __builtin_amdgcn_s_sleep(2);
  }
  __syncthreads();
  __threadfence();
}

// Repack core: 256 lanes x nt k-tiles (swizzled blob layout:
// fragment octet c8 = p^((n>>1)&3), bf16x8 sequential out).
__device__ __forceinline__ void repack_unit(const float* __restrict__ src,
                                            bf16_t* __restrict__ dst, int C,
                                            int kc0, int tid, int nt) {
  int n = tid >> 2, p4 = tid & 3;
  int c8 = p4 ^ ((n >> 1) & 3);
  const float* sp0 = src + n + (size_t)(kc0 * 32 + c8 * 8) * C;
  bf16_t* dp = dst + (size_t)kc0 * 2048 + tid * 8;
#pragma unroll 2
  for (int t = 0; t < nt; ++t) {
    const float* sp = sp0 + (size_t)t * 32 * C;
    float v[8];
#pragma unroll
    for (int j = 0; j < 8; ++j) v[j] = sp[(size_t)j * C];
    bf16x8 o;
#pragma unroll
    for (int j = 0; j < 8; ++j) o[j] = (bf16_t)v[j];
    *(bf16x8*)(dp + t * 2048) = o;
  }
}

union __attribute__((aligned(16))) SMem {
  struct { bf16_t A[128 * 32]; bf16_t B1[64 * 32]; bf16_t B3[64 * 32]; } g1;
  struct { bf16_t A[128 * 32]; bf16_t B[64 * 32]; } g2;
  struct { int2 sIdx[2048]; int sTot[16]; int sPos[8]; float sImp[4][8]; } sc;
};

__global__ void k_zero(int* bar) { if (threadIdx.x == 0) *bar = 0; }

__global__ __launch_bounds__(256, 4)
void k_moe(const float* __restrict__ x, const float* __restrict__ wg,
           const float* __restrict__ w1, const float* __restrict__ w3,
           const float* __restrict__ w2,
           bf16_t* __restrict__ xbf, bf16_t* __restrict__ w1b,
           bf16_t* __restrict__ w3b, bf16_t* __restrict__ w2b,
           bf16_t* __restrict__ h_ws, float* __restrict__ y,
           float* __restrict__ probs8, int2* __restrict__ idx2,
           float2* __restrict__ wc2, int* __restrict__ tok_of_row,
           int2* __restrict__ rows2, int2* __restrict__ cnt_start,
           float* __restrict__ out, int* bar) {
  __shared__ SMem sm;
  int bid = blockIdx.x;
  int tid = threadIdx.x;

  // ================= Phase A: routing (bid<512) + w1/w3 repack =================
  if (bid < 512) {
    int t = bid * 4 + (tid >> 6);
    int lane = tid & 63;
    const float* xr = x + (size_t)t * HD;
    int off = lane * 12;
    float4 a = *(const float4*)(xr + off);
    float4 bv = *(const float4*)(xr + off + 4);
    float4 c = *(const float4*)(xr + off + 8);
    float xv[12] = {a.x, a.y, a.z, a.w, bv.x, bv.y, bv.z, bv.w, c.x, c.y, c.z, c.w};
    bf16x4 s0, s1, s2;
#pragma unroll
    for (int j = 0; j < 4; ++j) { s0[j] = (bf16_t)xv[j]; s1[j] = (bf16_t)xv[4 + j]; s2[j] = (bf16_t)xv[8 + j]; }
    bf16_t* xo = xbf + (size_t)t * HD + off;
    *(bf16x4*)xo = s0; *(bf16x4*)(xo + 4) = s1; *(bf16x4*)(xo + 8) = s2;

    float acc[8] = {0, 0, 0, 0, 0, 0, 0, 0};
#pragma unroll
    for (int jj = 0; jj < 12; ++jj) {
      const float4* wr = (const float4*)(wg + (size_t)(off + jj) * 8);
      float4 w0 = wr[0], w1v = wr[1];
      float v = xv[jj];
      acc[0] += v * w0.x; acc[1] += v * w0.y; acc[2] += v * w0.z; acc[3] += v * w0.w;
      acc[4] += v * w1v.x; acc[5] += v * w1v.y; acc[6] += v * w1v.z; acc[7] += v * w1v.w;
    }
#pragma unroll
    for (int e = 0; e < 8; ++e) {
      float v = acc[e];
      for (int s = 1; s < 64; s <<= 1) v += __shfl_xor(v, s, 64);
      acc[e] = v;
    }
    float mx = acc[0];
#pragma unroll
    for (int e = 1; e < 8; ++e) mx = fmaxf(mx, acc[e]);
    float p[8], sum = 0.f;
#pragma unroll
    for (int e = 0; e < 8; ++e) { p[e] = __expf(acc[e] - mx); sum += p[e]; }
#pragma unroll
    for (int e = 0; e < 8; ++e) p[e] /= sum;
    if (lane == 0) {
      float4 P0 = make_float4(p[0], p[1], p[2], p[3]);
      float4 P1 = make_float4(p[4], p[5], p[6], p[7]);
      *(float4*)&probs8[t * 8] = P0;
      *(float4*)&probs8[t * 8 + 4] = P1;
      int e0 = 0;
#pragma unroll
      for (int e = 1; e < 8; ++e) if (p[e] > p[e0]) e0 = e;
      int e1 = (e0 == 0) ? 1 : 0;
#pragma unroll
      for (int e = 0; e < 8; ++e) if (e != e0 && p[e] > p[e1]) e1 = e;
      float denom = p[e0] + p[e1] + 1e-8f;
      float w0c = fminf(fmaxf(p[e0] / denom, 1e-8f), 10.f);
      float w1c = fminf(fmaxf(p[e1] / denom, 1e-8f), 10.f);
      idx2[t] = make_int2(e0, e1);
      wc2[t] = make_float2(w0c, w1c);
    }
  }
  for (int u = bid; u < 1152; u += GRID) {  // 576 w1 + 576 w3 units (8 ktiles)
    int m = u >= 576;
    int r3 = m ? u - 576 : u;
    int pan = r3 / 3;
    int kc0 = (r3 - pan * 3) * 8;
    int e = pan & 7, nb = pan >> 3;
    const float* src = (m ? w3 : w1) + (size_t)e * HD * ID + nb * 64;
    bf16_t* dst = (m ? w3b : w1b) + (size_t)(e * NB1 + nb) * (KC1 * 2048);
    repack_unit(src, dst, ID, kc0, tid, 8);
  }
  gridbar(bar, 1 * GRID);

  // ================= Phase B: scan (block 0) || w2 repack (others) =================
  if (bid == 0) {
    int2* sIdx = sm.sc.sIdx;
#pragma unroll
    for (int k = 0; k < 8; ++k) sIdx[tid + 256 * k] = idx2[tid + 256 * k];
#pragma unroll
    for (int k = 0; k < 8; ++k) rows2[tid + 256 * k] = make_int2(-1, -1);
    const float4* pp = (const float4*)probs8;
    float im[8] = {0, 0, 0, 0, 0, 0, 0, 0};
#pragma unroll
    for (int k = 0; k < 4; ++k) {
      int T = tid + 256 * k;
      float4 u0 = pp[T * 4], u1 = pp[T * 4 + 1], u2 = pp[T * 4 + 2], u3 = pp[T * 4 + 3];
      im[0] += u0.x + u2.x; im[1] += u0.y + u2.y; im[2] += u0.z + u2.z; im[3] += u0.w + u2.w;
      im[4] += u1.x + u3.x; im[5] += u1.y + u3.y; im[6] += u1.z + u3.z; im[7] += u1.w + u3.w;
    }
#pragma unroll
    for (int e = 0; e < 8; ++e) {
      float v = im[e];
      for (int d = 1; d < 64; d <<= 1) v += __shfl_xor(v, d, 64);
      im[e] = v;
    }
    int w = tid >> 6, lane = tid & 63;
    if (lane == 0) {
#pragma unroll
      for (int e = 0; e < 8; ++e) sm.sc.sImp[w][e] = im[e];
    }
    __syncthreads();
    int t0 = lane * 32;
    int excl4[4];
#pragma unroll
    for (int sub = 0; sub < 4; ++sub) {
      int pair = w * 4 + sub;
      int s = pair >> 3, e = pair & 7;
      int cnt = 0;
      for (int j = 0; j < 32; ++j) {
        int2 p = sIdx[t0 + j];
        cnt += ((s ? p.y : p.x) == e) ? 1 : 0;
      }
      int incl = cnt;
      for (int d = 1; d < 64; d <<= 1) {
        int v = __shfl_up(incl, d, 64);
        if (lane >= d) incl += v;
      }
      excl4[sub] = incl - cnt;
      if (lane == 63) sm.sc.sTot[pair] = incl;
    }
    __syncthreads();
    if (tid == 0) {
      int run = 0; float a = 0.f;
      for (int ee = 0; ee < 8; ++ee) {
        float impv = sm.sc.sImp[0][ee] + sm.sc.sImp[1][ee] + sm.sc.sImp[2][ee] + sm.sc.sImp[3][ee];
        int k = min(sm.sc.sTot[ee], CAP) + min(sm.sc.sTot[8 + ee], CAP);
        sm.sc.sPos[ee] = run;
        cnt_start[ee] = make_int2(run, k);
        a += ((float)k / (float)TK) * (impv / (float)T_TOK);
        run += k;
      }
      a *= (float)NE;
      int dropped = TK - run;
      if (dropped > 0) a += (float)dropped / (float)T_TOK * 0.1f;
      out[(size_t)T_TOK * HD] = fminf(a, 1.f) * 0.001f;  // aux
    }
    __syncthreads();
#pragma unroll
    for (int sub = 0; sub < 4; ++sub) {
      int pair = w * 4 + sub;
      int s = pair >> 3, e = pair & 7;
      int rank = excl4[sub];
      for (int j = 0; j < 32; ++j) {
        int t = t0 + j;
        int2 p = sIdx[t];
        int ex = s ? p.y : p.x;
        if (ex == e) {
          rank++;
          if (rank <= CAP) {
            int pos = atomicAdd(&sm.sc.sPos[e], 1);
            tok_of_row[pos] = t;
            ((int*)rows2)[2 * t + s] = pos;
          }
        }
      }
    }
  } else {
    for (int u = bid - 1; u < 1152; u += GRID - 1) {  // w2 half-units (4 ktiles)
      int pan = u / 12;
      int kc0 = (u - pan * 12) * 4;
      int e = pan & 7, nb = pan >> 3;
      const float* src = w2 + (size_t)e * ID * HD + nb * 64;
      bf16_t* dst = w2b + (size_t)(e * NB2 + nb) * (KC2 * 2048);
      repack_unit(src, dst, HD, kc0, tid, 4);
    }
  }
  gridbar(bar, 2 * GRID);

  // ================= Phase C: grouped GEMM1 (g,u) + SiLU -> h =================
  {
    int lane = tid & 63, wv = tid >> 6;
    int wm = wv & 1, wn = wv >> 1;
    int lr = lane & 15, q = lane >> 4;
    int rdc = (q ^ ((lane >> 1) & 3)) * 8;
    int srow = lane >> 2;
    int gch = ((lane & 3) ^ ((lane >> 3) & 3)) * 8;
    bf16_t* lA0 = &sm.g1.A[(wv * 32) * 32];
    bf16_t* lA1 = &sm.g1.A[(wv * 32 + 16) * 32];
    bf16_t* lB1 = &sm.g1.B1[wv * 512];
    bf16_t* lB3 = &sm.g1.B3[wv * 512];
    for (int tile = bid; tile < 8 * NB1 * RT; tile += GRID) {
      int e = tile & 7;
      int t = tile >> 3;
      int nb = t / RT, rt = t - nb * RT;
      int2 cs = cnt_start[e];
      int nrows = cs.y - rt * 128;
      if (nrows <= 0) continue;
      if (nrows > 128) nrows = 128;
      int grow0 = cs.x + rt * 128;

      int ra = wv * 32 + srow;
      int tokA0 = tok_of_row[grow0 + min(ra, nrows - 1)];
      int tokA1 = tok_of_row[grow0 + min(ra + 16, nrows - 1)];
      const bf16_t* gA0 = xbf + (size_t)tokA0 * HD + gch;
      const bf16_t* gA1 = xbf + (size_t)tokA1 * HD + gch;
      const bf16_t* p1 = w1b + (size_t)((e * NB1 + nb) * KC1) * 2048 + tid * 8;
      const bf16_t* p3 = w3b + (size_t)((e * NB1 + nb) * KC1) * 2048 + tid * 8;

      floatx4 accg[4][2] = {};
      floatx4 accu[4][2] = {};

      for (int kk = 0; kk < KC1; ++kk) {
        __syncthreads();
        gld16(gA0, lA0); gld16(gA1, lA1);
        gld16(p1, lB1); gld16(p3, lB3);
        gA0 += 32; gA1 += 32; p1 += 2048; p3 += 2048;
        __syncthreads();
        bf16x8 af[4], b1f[2], b3f[2];
#pragma unroll
        for (int i = 0; i < 4; ++i) af[i] = *(const bf16x8*)&sm.g1.A[(wm * 64 + i * 16 + lr) * 32 + rdc];
#pragma unroll
        for (int i = 0; i < 2; ++i) b1f[i] = *(const bf16x8*)&sm.g1.B1[(wn * 32 + i * 16 + lr) * 32 + rdc];
#pragma unroll
        for (int i = 0; i < 2; ++i) b3f[i] = *(const bf16x8*)&sm.g1.B3[(wn * 32 + i * 16 + lr) * 32 + rdc];
#pragma unroll
        for (int i = 0; i < 4; ++i)
#pragma unroll
          for (int jj = 0; jj < 2; ++jj) {
            accg[i][jj] = __builtin_amdgcn_mfma_f32_16x16x32_bf16(af[i], b1f[jj], accg[i][jj], 0, 0, 0);
            accu[i][jj] = __builtin_amdgcn_mfma_f32_16x16x32_bf16(af[i], b3f[jj], accu[i][jj], 0, 0, 0);
          }
      }
      __syncthreads();
#pragma unroll
      for (int i = 0; i < 4; ++i)
#pragma unroll
        for (int r = 0; r < 4; ++r) {
          int rl = wm * 64 + i * 16 + q * 4 + r;
          if (rl < nrows) {
            size_t rb = (size_t)(grow0 + rl) * ID + nb * 64 + wn * 32 + lr;
#pragma unroll
            for (int jj = 0; jj < 2; ++jj) {
              float gg = accg[i][jj][r], uu = accu[i][jj][r];
              float sg = gg / (1.f + __expf(-gg));
              h_ws[rb + jj * 16] = (bf16_t)(sg * uu);
            }
          }
        }
    }
  }
  gridbar(bar, 3 * GRID);

  // ================= Phase D: grouped GEMM2 -> y =================
  {
    int lane = tid & 63, wv = tid >> 6;
    int wm = wv & 1, wn = wv >> 1;
    int lr = lane & 15, q = lane >> 4;
    int rdc = (q ^ ((lane >> 1) & 3)) * 8;
    int srow = lane >> 2;
    int gch = ((lane & 3) ^ ((lane >> 3) & 3)) * 8;
    bf16_t* lA0 = &sm.g2.A[(wv * 32) * 32];
    bf16_t* lA1 = &sm.g2.A[(wv * 32 + 16) * 32];
    bf16_t* lB = &sm.g2.B[wv * 512];
    for (int tile = bid; tile < 8 * NB2 * RT; tile += GRID) {
      int e = tile & 7;
      int t = tile >> 3;
      int nb = t / RT, rt = t - nb * RT;
      int2 cs = cnt_start[e];
      int nrows = cs.y - rt * 128;
      if (nrows <= 0) continue;
      if (nrows > 128) nrows = 128;
      int grow0 = cs.x + rt * 128;

      int ra = wv * 32 + srow;
      const bf16_t* gA0 = h_ws + (size_t)(grow0 + min(ra, nrows - 1)) * ID + gch;
      const bf16_t* gA1 = h_ws + (size_t)(grow0 + min(ra + 16, nrows - 1)) * ID + gch;
      const bf16_t* pB = w2b + (size_t)((e * NB2 + nb) * KC2) * 2048 + tid * 8;

      floatx4 acc[4][2] = {};

      for (int kk = 0; kk < KC2; ++kk) {
        __syncthreads();
        gld16(gA0, lA0); gld16(gA1, lA1);
        gld16(pB, lB);
        gA0 += 32; gA1 += 32; pB += 2048;
        __syncthreads();
        bf16x8 af[4], bfr[2];
#pragma unroll
        for (int i = 0; i < 4; ++i) af[i] = *(const bf16x8*)&sm.g2.A[(wm * 64 + i * 16 + lr) * 32 + rdc];
#pragma unroll
        for (int i = 0; i < 2; ++i) bfr[i] = *(const bf16x8*)&sm.g2.B[(wn * 32 + i * 16 + lr) * 32 + rdc];
#pragma unroll
        for (int i = 0; i < 4; ++i)
#pragma unroll
          for (int jj = 0; jj < 2; ++jj)
            acc[i][jj] = __builtin_amdgcn_mfma_f32_16x16x32_bf16(af[i], bfr[jj], acc[i][jj], 0, 0, 0);
      }
      __syncthreads();
#pragma unroll
      for (int i = 0; i < 4; ++i)
#pragma unroll
        for (int r = 0; r < 4; ++r) {
          int rl = wm * 64 + i * 16 + q * 4 + r;
          if (rl < nrows) {
            size_t ob = (size_t)(grow0 + rl) * HD + nb * 64 + wn * 32 + lr;
#pragma unroll
            for (int jj = 0; jj < 2; ++jj)
              y[ob + jj * 16] = acc[i][jj][r];
          }
        }
    }
  }
  gridbar(bar, 4 * GRID);

  // ================= Phase E: combine =================
  if (bid < 512) {
    int t = bid * 4 + (tid >> 6);
    int lane = tid & 63;
    int2 r = rows2[t];
    float2 w = wc2[t];
    int off = lane * 12;
    floatx4 o0 = {0.f, 0.f, 0.f, 0.f}, o1 = o0, o2 = o0;
    if (r.x >= 0) {
      const float* yr = y + (size_t)r.x * HD + off;
      floatx4 a = *(const floatx4*)(yr);
      floatx4 b = *(const floatx4*)(yr + 4);
      floatx4 c = *(const floatx4*)(yr + 8);
      o0 += w.x * a; o1 += w.x * b; o2 += w.x * c;
    }
    if (r.y >= 0) {
      const float* yr = y + (size_t)r.y * HD + off;
      floatx4 a = *(const floatx4*)(yr);
      floatx4 b = *(const floatx4*)(yr + 4);
      floatx4 c = *(const floatx4*)(yr + 8);
      o0 += w.y * a; o1 += w.y * b; o2 += w.y * c;
    }
    float* op = out + (size_t)t * HD + off;
    *(floatx4*)(op) = o0;
    *(floatx4*)(op + 4) = o1;
    *(floatx4*)(op + 8) = o2;
  }
}

extern "C" void kernel_launch(void* const* d_in, const int* in_sizes, int n_in,
                              void* d_out, int out_size, void* d_ws, size_t ws_size,
                              hipStream_t stream) {
  const float* x  = (const float*)d_in[0];
  const float* wg = (const float*)d_in[1];
  const float* w1 = (const float*)d_in[2];
  const float* w3 = (const float*)d_in[3];
  const float* w2 = (const float*)d_in[4];
  float* out = (float*)d_out;

  char* ws = (char*)d_ws;
  bf16_t* xbf  = (bf16_t*)(ws + 0);          //  3,145,728
  bf16_t* w1b  = (bf16_t*)(ws + 3145728);    // 18,874,368
  bf16_t* w3b  = (bf16_t*)(ws + 22020096);   // 18,874,368
  bf16_t* w2b  = (bf16_t*)(ws + 40894464);   // 18,874,368
  bf16_t* h_ws = (bf16_t*)(ws + 59768832);   // 12,582,912
  float*  probs8     = (float*)(ws + 72351744);   // 65,536
  int2*   idx2       = (int2*)(ws + 72417280);
  float2* wc2        = (float2*)(ws + 72433664);
  int*    tok_of_row = (int*)(ws + 72450048);
  int2*   rows2      = (int2*)(ws + 72466432);
  int2*   cnt_start  = (int2*)(ws + 72482816);
  int*    bar        = (int*)(ws + 72483840);
  // y_ws (4096*768 fp32 = 12.58 MB) aliases w1b: w1b is dead after phase C,
  // and phase D (which writes y) is grid-barrier-ordered after phase C.
  float*  y_ws = (float*)(ws + 3145728);

  k_zero<<<1, 64, 0, stream>>>(bar);
  k_moe<<<GRID, 256, 0, stream>>>(x, wg, w1, w3, w2, xbf, w1b, w3b, w2b, h_ws,
                                  y_ws, probs8, idx2, wc2, tok_of_row, rows2,
                                  cnt_start, out, bar);
}

// Round 9
// 231.469 us; speedup vs baseline: 5.4035x; 5.4035x over previous
//
#include <hip/hip_runtime.h>
#include <math.h>

#define T_TOK 2048
#define HD 768
#define ID 1536
#define NE 8
#define CAP 768
#define TK 4096
#define RT 12      // max 128-row tiles per expert (2*CAP/128)
#define NB1 24     // ID/64 col-strips for gemm1
#define KC1 24     // HD/32 K-steps for gemm1
#define NB2 12     // HD/64 col-strips for gemm2
#define KC2 48     // ID/32 K-steps for gemm2
#define W2BLK 576  // w2 repack blocks prepended to gemm1 grid

typedef __bf16 bf16_t;
typedef __bf16 bf16x8 __attribute__((ext_vector_type(8)));
typedef __bf16 bf16x4 __attribute__((ext_vector_type(4)));
typedef float floatx4 __attribute__((ext_vector_type(4)));

__device__ __forceinline__ void gld16(const bf16_t* g, bf16_t* l) {
  __builtin_amdgcn_global_load_lds(
      (__attribute__((address_space(1))) void*)(g),
      (__attribute__((address_space(3))) void*)(l),
      16, 0, 0);
}

__device__ __forceinline__ unsigned short bfbits(float f) {
  union { bf16_t b; unsigned short u; } c;
  c.b = (bf16_t)f;
  return c.u;
}

// ---- Coalesced repack of one k-tile (32 rows x 64 cols fp32 -> blob bf16) ----
// Phase 1 (rp_load): thread t256 reads 2 x float4 from row r=t256>>3, cols
// (t256&7)*8.. — 16B/lane coalesced — converts to bf16 pairs and writes u32s
// into padded LDS tile T32 = [32][33] u32 (= [32][66] bf16; <=2-way banks).
// Phase 2 (rp_store): thread t256 (n=t>>2, p4=t&3, c8=p4^((n>>1)&3)) gathers
// LDS[(c8*8+j)][n] for j=0..7 (<=2-way banks) and stores one 16B blob chunk:
// dst[kc*2048 + t256*8 + j] = src[(kc*32 + c8*8 + j)*C + n]  (layout identical
// to the original scalar repack).
__device__ __forceinline__ void rp_load(const float* __restrict__ src, int C,
                                        int kc, int t256, unsigned* T32) {
  int r = t256 >> 3, c0 = (t256 & 7) * 8;
  const float* sp = src + (size_t)(kc * 32 + r) * C + c0;
  float4 v0 = *(const float4*)sp;
  float4 v1 = *(const float4*)(sp + 4);
  float f[8] = {v0.x, v0.y, v0.z, v0.w, v1.x, v1.y, v1.z, v1.w};
  unsigned* tb = T32 + r * 33 + (c0 >> 1);
#pragma unroll
  for (int k = 0; k < 4; ++k)
    tb[k] = (unsigned)bfbits(f[2 * k]) | ((unsigned)bfbits(f[2 * k + 1]) << 16);
}

__device__ __forceinline__ void rp_store(bf16_t* __restrict__ dst, int kc,
                                         int t256, const unsigned* T32) {
  int n = t256 >> 2, p4 = t256 & 3;
  int c8 = p4 ^ ((n >> 1) & 3);
  int half = n & 1, nh = n >> 1;
  unsigned short u[8];
#pragma unroll
  for (int j = 0; j < 8; ++j) {
    unsigned w = T32[(c8 * 8 + j) * 33 + nh];
    u[j] = half ? (unsigned short)(w >> 16) : (unsigned short)(w & 0xffffu);
  }
  uint4 o;
  o.x = (unsigned)u[0] | ((unsigned)u[1] << 16);
  o.y = (unsigned)u[2] | ((unsigned)u[3] << 16);
  o.z = (unsigned)u[4] | ((unsigned)u[5] << 16);
  o.w = (unsigned)u[6] | ((unsigned)u[7] << 16);
  *(uint4*)(dst + (size_t)kc * 2048 + t256 * 8) = o;
}

// ---------------- K1: routing only (4 tokens/block, wave per token) ----------------
__global__ void k_route(const float* __restrict__ x, const float* __restrict__ wg,
                        bf16_t* __restrict__ xbf, int2* __restrict__ idx2,
                        float2* __restrict__ wc2, float* __restrict__ probs8) {
  int b = blockIdx.x;
  int tid = threadIdx.x;
  int t = b * 4 + (tid >> 6);
  int lane = tid & 63;
  const float* xr = x + (size_t)t * HD;
  int off = lane * 12;
  float4 a = *(const float4*)(xr + off);
  float4 bv = *(const float4*)(xr + off + 4);
  float4 c = *(const float4*)(xr + off + 8);
  float xv[12] = {a.x, a.y, a.z, a.w, bv.x, bv.y, bv.z, bv.w, c.x, c.y, c.z, c.w};
  bf16x4 s0, s1, s2;
#pragma unroll
  for (int j = 0; j < 4; ++j) { s0[j] = (bf16_t)xv[j]; s1[j] = (bf16_t)xv[4 + j]; s2[j] = (bf16_t)xv[8 + j]; }
  bf16_t* xo = xbf + (size_t)t * HD + off;
  *(bf16x4*)xo = s0; *(bf16x4*)(xo + 4) = s1; *(bf16x4*)(xo + 8) = s2;

  float acc[8] = {0, 0, 0, 0, 0, 0, 0, 0};
#pragma unroll
  for (int jj = 0; jj < 12; ++jj) {
    const float4* wr = (const float4*)(wg + (size_t)(off + jj) * 8);
    float4 w0 = wr[0], w1v = wr[1];
    float v = xv[jj];
    acc[0] += v * w0.x; acc[1] += v * w0.y; acc[2] += v * w0.z; acc[3] += v * w0.w;
    acc[4] += v * w1v.x; acc[5] += v * w1v.y; acc[6] += v * w1v.z; acc[7] += v * w1v.w;
  }
#pragma unroll
  for (int e = 0; e < 8; ++e) {
    float v = acc[e];
    for (int s = 1; s < 64; s <<= 1) v += __shfl_xor(v, s, 64);
    acc[e] = v;
  }
  float mx = acc[0];
#pragma unroll
  for (int e = 1; e < 8; ++e) mx = fmaxf(mx, acc[e]);
  float p[8], sum = 0.f;
#pragma unroll
  for (int e = 0; e < 8; ++e) { p[e] = __expf(acc[e] - mx); sum += p[e]; }
#pragma unroll
  for (int e = 0; e < 8; ++e) p[e] /= sum;
  if (lane == 0) {
    float4 P0 = make_float4(p[0], p[1], p[2], p[3]);
    float4 P1 = make_float4(p[4], p[5], p[6], p[7]);
    *(float4*)&probs8[t * 8] = P0;
    *(float4*)&probs8[t * 8 + 4] = P1;
    int e0 = 0;
#pragma unroll
    for (int e = 1; e < 8; ++e) if (p[e] > p[e0]) e0 = e;
    int e1 = (e0 == 0) ? 1 : 0;
#pragma unroll
    for (int e = 0; e < 8; ++e) if (e != e0 && p[e] > p[e1]) e1 = e;
    float denom = p[e0] + p[e1] + 1e-8f;
    float w0c = fminf(fmaxf(p[e0] / denom, 1e-8f), 10.f);
    float w1c = fminf(fmaxf(p[e1] / denom, 1e-8f), 10.f);
    idx2[t] = make_int2(e0, e1);
    wc2[t] = make_float2(w0c, w1c);
  }
}

// ---------------- K2: scan (block 0) + w1/w3 coalesced repack (blocks 1..1152) ----------------
__global__ void k_scan(const int2* __restrict__ idx2, const float2* __restrict__ wc2,
                       const float* __restrict__ probs8,
                       const float* __restrict__ w1, const float* __restrict__ w3,
                       bf16_t* __restrict__ w1b, bf16_t* __restrict__ w3b,
                       int* __restrict__ tok_of_row, int2* __restrict__ rows2,
                       int2* __restrict__ cnt_start, float* __restrict__ aux_out) {
  __shared__ unsigned sTr[4 * 2 * 1056];  // 4 groups x 2 tiles x [32][33] u32
  if (blockIdx.x > 0) {
    // coalesced w1/w3 repack, overlapped with the single-block scan
    int rb = blockIdx.x - 1;  // [0,1152): 576 w1 + 576 w3
    int m = rb >= 576;
    int r3 = m ? rb - 576 : rb;
    int pan = r3 / 3;
    int kc0 = (r3 - pan * 3) * 8;
    int e = pan & 7, nb = pan >> 3;
    const float* src = (m ? w3 : w1) + (size_t)e * HD * ID + nb * 64;
    bf16_t* dst = (m ? w3b : w1b) + (size_t)(e * NB1 + nb) * (KC1 * 2048);
    int grp = threadIdx.x >> 8, lt = threadIdx.x & 255;
    unsigned* T0 = sTr + grp * 2 * 1056;
    unsigned* T1 = T0 + 1056;
    int kc = kc0 + grp * 2;
    rp_load(src, ID, kc, lt, T0);
    __syncthreads();
    rp_load(src, ID, kc + 1, lt, T1);
    rp_store(dst, kc, lt, T0);
    __syncthreads();
    rp_store(dst, kc + 1, lt, T1);
    return;
  }
  __shared__ int2 sIdx[2048];
  __shared__ int sTot[16];
  __shared__ int sPos[8];
  __shared__ float sImp[16][8];
  int tid = threadIdx.x;
  sIdx[tid] = idx2[tid]; sIdx[tid + 1024] = idx2[tid + 1024];
  rows2[tid] = make_int2(-1, -1); rows2[tid + 1024] = make_int2(-1, -1);
  const float4* pp = (const float4*)probs8;
  float4 u0 = pp[tid * 4], u1 = pp[tid * 4 + 1], u2 = pp[tid * 4 + 2], u3 = pp[tid * 4 + 3];
  float im[8] = {u0.x + u2.x, u0.y + u2.y, u0.z + u2.z, u0.w + u2.w,
                 u1.x + u3.x, u1.y + u3.y, u1.z + u3.z, u1.w + u3.w};
#pragma unroll
  for (int e = 0; e < 8; ++e) {
    float v = im[e];
    for (int d = 1; d < 64; d <<= 1) v += __shfl_xor(v, d, 64);
    im[e] = v;
  }
  int w = tid >> 6, lane = tid & 63;
  if (lane == 0) {
#pragma unroll
    for (int e = 0; e < 8; ++e) sImp[w][e] = im[e];
  }
  __syncthreads();
  int s = w >> 3, e = w & 7;
  int t0 = lane * 32;
  int cnt = 0;
  for (int j = 0; j < 32; ++j) {
    int2 p = sIdx[t0 + j];
    cnt += ((s ? p.y : p.x) == e) ? 1 : 0;
  }
  int incl = cnt;
  for (int d = 1; d < 64; d <<= 1) {
    int v = __shfl_up(incl, d, 64);
    if (lane >= d) incl += v;
  }
  int excl = incl - cnt;
  if (lane == 63) sTot[w] = incl;
  __syncthreads();
  if (tid == 0) {
    int run = 0; float a = 0.f;
    for (int ee = 0; ee < 8; ++ee) {
      float impv = 0.f;
      for (int ww = 0; ww < 16; ++ww) impv += sImp[ww][ee];
      int k = min(sTot[ee], CAP) + min(sTot[8 + ee], CAP);
      sPos[ee] = run;
      cnt_start[ee] = make_int2(run, k);
      a += ((float)k / (float)TK) * (impv / (float)T_TOK);
      run += k;
    }
    a *= (float)NE;
    int dropped = TK - run;
    if (dropped > 0) a += (float)dropped / (float)T_TOK * 0.1f;
    aux_out[0] = fminf(a, 1.f) * 0.001f;
  }
  __syncthreads();
  int rank = excl;
  for (int j = 0; j < 32; ++j) {
    int t = t0 + j;
    int2 p = sIdx[t];
    int ex = s ? p.y : p.x;
    if (ex == e) {
      rank++;
      if (rank <= CAP) {
        int pos = atomicAdd(&sPos[e], 1);
        tok_of_row[pos] = t;
        ((int*)rows2)[2 * t + s] = pos;
      }
    }
  }
}

// ---------------- K3: w2 coalesced repack (blocks 0..575) + grouped GEMM1 ----------------
// gemm blocks: bx = e + 8*(nb*RT + rt); tile 128m x 64n
__global__ __launch_bounds__(256, 4)
void k_gemm1(const bf16_t* __restrict__ xbf, const bf16_t* __restrict__ w1b,
             const bf16_t* __restrict__ w3b, const float* __restrict__ w2,
             bf16_t* __restrict__ w2b, const int* __restrict__ tok_of_row,
             const int2* __restrict__ cnt_start, bf16_t* __restrict__ h_ws) {
  __shared__ __attribute__((aligned(16))) bf16_t Abuf[128 * 32];
  __shared__ __attribute__((aligned(16))) bf16_t B1buf[64 * 32];
  __shared__ __attribute__((aligned(16))) bf16_t B3buf[64 * 32];
  __shared__ unsigned Trp[2 * 1056];
  if (blockIdx.x < W2BLK) {
    // coalesced w2 repack (8 k-tiles, double-buffered LDS transpose)
    int q = blockIdx.x;
    int pan = q / 6;
    int kc0 = (q - pan * 6) * 8;
    int e = pan & 7, nb = pan >> 3;
    const float* src = w2 + (size_t)e * ID * HD + nb * 64;
    bf16_t* dst = w2b + (size_t)(e * NB2 + nb) * (KC2 * 2048);
    int tid = threadIdx.x;
    rp_load(src, HD, kc0, tid, Trp);
    for (int t = 0; t < 8; ++t) {
      __syncthreads();  // tile t's LDS writes visible
      if (t < 7) rp_load(src, HD, kc0 + t + 1, tid, Trp + ((t + 1) & 1) * 1056);
      rp_store(dst, kc0 + t, tid, Trp + (t & 1) * 1056);
    }
    return;
  }
  int bx = blockIdx.x - W2BLK;
  int e = bx & 7;
  int t = bx >> 3;
  int nb = t / RT, rt = t - nb * RT;
  int2 cs = cnt_start[e];
  int nrows = cs.y - rt * 128;
  if (nrows <= 0) return;
  if (nrows > 128) nrows = 128;
  int grow0 = cs.x + rt * 128;

  int tid = threadIdx.x;
  int lane = tid & 63, wv = tid >> 6;
  int wm = wv & 1, wn = wv >> 1;
  int lr = lane & 15, q = lane >> 4;
  int rdc = (q ^ ((lane >> 1) & 3)) * 8;
  int srow = lane >> 2;
  int gch = ((lane & 3) ^ ((lane >> 3) & 3)) * 8;

  int ra = wv * 32 + srow;
  int tokA0 = tok_of_row[grow0 + min(ra, nrows - 1)];
  int tokA1 = tok_of_row[grow0 + min(ra + 16, nrows - 1)];
  const bf16_t* gA0 = xbf + (size_t)tokA0 * HD + gch;
  const bf16_t* gA1 = xbf + (size_t)tokA1 * HD + gch;
  const bf16_t* p1 = w1b + (size_t)((e * NB1 + nb) * KC1) * 2048 + tid * 8;
  const bf16_t* p3 = w3b + (size_t)((e * NB1 + nb) * KC1) * 2048 + tid * 8;
  bf16_t* lA0 = &Abuf[(wv * 32) * 32];
  bf16_t* lA1 = &Abuf[(wv * 32 + 16) * 32];
  bf16_t* lB1 = &B1buf[wv * 512];
  bf16_t* lB3 = &B3buf[wv * 512];

  floatx4 accg[4][2] = {};
  floatx4 accu[4][2] = {};

  for (int kk = 0; kk < KC1; ++kk) {
    __syncthreads();
    gld16(gA0, lA0); gld16(gA1, lA1);
    gld16(p1, lB1); gld16(p3, lB3);
    gA0 += 32; gA1 += 32; p1 += 2048; p3 += 2048;
    __syncthreads();
    bf16x8 af[4], b1f[2], b3f[2];
#pragma unroll
    for (int i = 0; i < 4; ++i) af[i] = *(const bf16x8*)&Abuf[(wm * 64 + i * 16 + lr) * 32 + rdc];
#pragma unroll
    for (int i = 0; i < 2; ++i) b1f[i] = *(const bf16x8*)&B1buf[(wn * 32 + i * 16 + lr) * 32 + rdc];
#pragma unroll
    for (int i = 0; i < 2; ++i) b3f[i] = *(const bf16x8*)&B3buf[(wn * 32 + i * 16 + lr) * 32 + rdc];
#pragma unroll
    for (int i = 0; i < 4; ++i)
#pragma unroll
      for (int jj = 0; jj < 2; ++jj) {
        accg[i][jj] = __builtin_amdgcn_mfma_f32_16x16x32_bf16(af[i], b1f[jj], accg[i][jj], 0, 0, 0);
        accu[i][jj] = __builtin_amdgcn_mfma_f32_16x16x32_bf16(af[i], b3f[jj], accu[i][jj], 0, 0, 0);
      }
  }
#pragma unroll
  for (int i = 0; i < 4; ++i)
#pragma unroll
    for (int r = 0; r < 4; ++r) {
      int rl = wm * 64 + i * 16 + q * 4 + r;
      if (rl < nrows) {
        size_t rb = (size_t)(grow0 + rl) * ID + nb * 64 + wn * 32 + lr;
#pragma unroll
        for (int jj = 0; jj < 2; ++jj) {
          float gg = accg[i][jj][r], uu = accu[i][jj][r];
          float sg = gg / (1.f + __expf(-gg));
          h_ws[rb + jj * 16] = (bf16_t)(sg * uu);
        }
      }
    }
}

// ---------------- K4: grouped GEMM2, plain fp32 stores to per-slot y ----------------
// grid 1152: bx = e + 8*(nb*RT + rt); tile 128m x 64n
__global__ __launch_bounds__(256, 4)
void k_gemm2(const bf16_t* __restrict__ h_ws, const bf16_t* __restrict__ w2b,
             const int2* __restrict__ cnt_start, float* __restrict__ y) {
  int e = blockIdx.x & 7;
  int t = blockIdx.x >> 3;
  int nb = t / RT, rt = t - nb * RT;
  int2 cs = cnt_start[e];
  int nrows = cs.y - rt * 128;
  if (nrows <= 0) return;
  if (nrows > 128) nrows = 128;
  int grow0 = cs.x + rt * 128;

  __shared__ __attribute__((aligned(16))) bf16_t Abuf[128 * 32];
  __shared__ __attribute__((aligned(16))) bf16_t Bbuf[64 * 32];

  int tid = threadIdx.x;
  int lane = tid & 63, wv = tid >> 6;
  int wm = wv & 1, wn = wv >> 1;
  int lr = lane & 15, q = lane >> 4;
  int rdc = (q ^ ((lane >> 1) & 3)) * 8;
  int srow = lane >> 2;
  int gch = ((lane & 3) ^ ((lane >> 3) & 3)) * 8;

  int ra = wv * 32 + srow;
  const bf16_t* gA0 = h_ws + (size_t)(grow0 + min(ra, nrows - 1)) * ID + gch;
  const bf16_t* gA1 = h_ws + (size_t)(grow0 + min(ra + 16, nrows - 1)) * ID + gch;
  const bf16_t* pB = w2b + (size_t)((e * NB2 + nb) * KC2) * 2048 + tid * 8;
  bf16_t* lA0 = &Abuf[(wv * 32) * 32];
  bf16_t* lA1 = &Abuf[(wv * 32 + 16) * 32];
  bf16_t* lB = &Bbuf[wv * 512];

  floatx4 acc[4][2] = {};

  for (int kk = 0; kk < KC2; ++kk) {
    __syncthreads();
    gld16(gA0, lA0); gld16(gA1, lA1);
    gld16(pB, lB);
    gA0 += 32; gA1 += 32; pB += 2048;
    __syncthreads();
    bf16x8 af[4], bfr[2];
#pragma unroll
    for (int i = 0; i < 4; ++i) af[i] = *(const bf16x8*)&Abuf[(wm * 64 + i * 16 + lr) * 32 + rdc];
#pragma unroll
    for (int i = 0; i < 2; ++i) bfr[i] = *(const bf16x8*)&Bbuf[(wn * 32 + i * 16 + lr) * 32 + rdc];
#pragma unroll
    for (int i = 0; i < 4; ++i)
#pragma unroll
      for (int jj = 0; jj < 2; ++jj)
        acc[i][jj] = __builtin_amdgcn_mfma_f32_16x16x32_bf16(af[i], bfr[jj], acc[i][jj], 0, 0, 0);
  }
#pragma unroll
  for (int i = 0; i < 4; ++i)
#pragma unroll
    for (int r = 0; r < 4; ++r) {
      int rl = wm * 64 + i * 16 + q * 4 + r;
      if (rl < nrows) {
        size_t ob = (size_t)(grow0 + rl) * HD + nb * 64 + wn * 32 + lr;
#pragma unroll
        for (int jj = 0; jj < 2; ++jj)
          y[ob + jj * 16] = acc[i][jj][r];
      }
    }
}

// ---------------- K5: combine out[t] = w0*y[r0] + w1*y[r1] (fully overwrites out) ----------------
__global__ void k_comb(const float* __restrict__ y, const int2* __restrict__ rows2,
                       const float2* __restrict__ wc2, float* __restrict__ out) {
  int tid = threadIdx.x;
  int t = blockIdx.x * 4 + (tid >> 6);
  int lane = tid & 63;
  int2 r = rows2[t];
  float2 w = wc2[t];
  int off = lane * 12;
  floatx4 o0 = {0.f, 0.f, 0.f, 0.f}, o1 = o0, o2 = o0;
  if (r.x >= 0) {
    const float* yr = y + (size_t)r.x * HD + off;
    floatx4 a = *(const floatx4*)(yr);
    floatx4 b = *(const floatx4*)(yr + 4);
    floatx4 c = *(const floatx4*)(yr + 8);
    o0 += w.x * a; o1 += w.x * b; o2 += w.x * c;
  }
  if (r.y >= 0) {
    const float* yr = y + (size_t)r.y * HD + off;
    floatx4 a = *(const floatx4*)(yr);
    floatx4 b = *(const floatx4*)(yr + 4);
    floatx4 c = *(const floatx4*)(yr + 8);
    o0 += w.y * a; o1 += w.y * b; o2 += w.y * c;
  }
  float* op = out + (size_t)t * HD + off;
  *(floatx4*)(op) = o0;
  *(floatx4*)(op + 4) = o1;
  *(floatx4*)(op + 8) = o2;
}

extern "C" void kernel_launch(void* const* d_in, const int* in_sizes, int n_in,
                              void* d_out, int out_size, void* d_ws, size_t ws_size,
                              hipStream_t stream) {
  const float* x  = (const float*)d_in[0];
  const float* wg = (const float*)d_in[1];
  const float* w1 = (const float*)d_in[2];
  const float* w3 = (const float*)d_in[3];
  const float* w2 = (const float*)d_in[4];
  float* out = (float*)d_out;

  char* ws = (char*)d_ws;
  bf16_t* xbf  = (bf16_t*)(ws + 0);          //  3,145,728
  bf16_t* w1b  = (bf16_t*)(ws + 3145728);    // 18,874,368
  bf16_t* w3b  = (bf16_t*)(ws + 22020096);   // 18,874,368
  bf16_t* w2b  = (bf16_t*)(ws + 40894464);   // 18,874,368
  bf16_t* h_ws = (bf16_t*)(ws + 59768832);   // 12,582,912
  float*  probs8     = (float*)(ws + 72351744);   // 65,536
  int2*   idx2       = (int2*)(ws + 72417280);
  float2* wc2        = (float2*)(ws + 72433664);
  int*    tok_of_row = (int*)(ws + 72450048);
  int2*   rows2      = (int2*)(ws + 72466432);
  int2*   cnt_start  = (int2*)(ws + 72482816);
  // y_ws (4096*768 fp32 = 12.58 MB) aliases w1b: w1b is dead once gemm1 completes,
  // and gemm2 (which writes y) is stream-ordered after gemm1.
  float*  y_ws = (float*)(ws + 3145728);

  float* aux_out = out + (size_t)T_TOK * HD;

  k_route<<<512, 256, 0, stream>>>(x, wg, xbf, idx2, wc2, probs8);
  k_scan<<<1 + 1152, 1024, 0, stream>>>(idx2, wc2, probs8, w1, w3, w1b, w3b,
                                        tok_of_row, rows2, cnt_start, aux_out);
  k_gemm1<<<W2BLK + 8 * NB1 * RT, 256, 0, stream>>>(xbf, w1b, w3b, w2, w2b,
                                                    tok_of_row, cnt_start, h_ws);
  k_gemm2<<<8 * NB2 * RT, 256, 0, stream>>>(h_ws, w2b, cnt_start, y_ws);
  k_comb<<<512, 256, 0, stream>>>(y_ws, rows2, wc2, out);
}